// Round 5
// baseline (308.881 us; speedup 1.0000x reference)
//
#include <hip/hip_runtime.h>

// Problem:
//   x:       (N=4096, C=64, 16, 16) f32
//   y_base:  (B=8, C=64, H=512, W=512) f32
//   indices: (N,3) int32 [b, r, c]; block origin (r*16, c*16); st==bs==16, off==0
//   out = y_base; out[b, :, r*16+i, c*16+j] += x[n, :, i, j]  (dups accumulate)
//
// Inverted-list + output-linear streaming. This round: 8-wide per-thread
// batching (more reads in flight per wave) + NT stores.

#define NPOS   8192
#define MAXDUP 16
#define OUT4   33554432            // 8*64*512*512 / 4
#define WGS    2048
#define CHUNK  (OUT4 / WGS)        // 16384 float4 per WG (256 KB)
#define MLP    8

typedef float v4f __attribute__((ext_vector_type(4)));

__global__ void zero_counts(int* __restrict__ cnt) {
    int i = blockIdx.x * 256 + threadIdx.x;
    if (i < NPOS) cnt[i] = 0;
}

__global__ void build_lists(const int* __restrict__ idx, int* __restrict__ cnt,
                            int* __restrict__ slots, int N) {
    int n = blockIdx.x * 256 + threadIdx.x;
    if (n >= N) return;
    const int b = idx[3 * n], r = idx[3 * n + 1], c = idx[3 * n + 2];
    const int pos = b * 1024 + r * 32 + c;
    const int s = atomicAdd(&cnt[pos], 1);
    if (s < MAXDUP) slots[pos * MAXDUP + s] = n;
}

__global__ void sort_lists(const int* __restrict__ cnt, int* __restrict__ slots) {
    int p = blockIdx.x * 256 + threadIdx.x;
    if (p >= NPOS) return;
    int nm = cnt[p]; if (nm > MAXDUP) nm = MAXDUP;
    int* s = slots + p * MAXDUP;
    for (int i = 1; i < nm; ++i) {
        const int key = s[i];
        int j = i - 1;
        while (j >= 0 && s[j] > key) { s[j + 1] = s[j]; --j; }
        s[j + 1] = key;
    }
}

__device__ __forceinline__ int pos_of(int i) {
    // i (float4 idx) bits: [b:3][c:6][h:9][w4:7]
    return (i >> 22) * 1024 + ((i >> 11) & 31) * 32 + ((i >> 2) & 31);
}
__device__ __forceinline__ int xbase_of(int i) {
    // float4 offset inside an x block: c*64 + (h&15)*4 + (w4&3)
    return ((i >> 16) & 63) * 64 + ((i >> 7) & 15) * 4 + (i & 3);
}

__global__ __launch_bounds__(256) void scatter_main(
    const v4f* __restrict__ x4,
    const v4f* __restrict__ yb4,
    const int* __restrict__ cnt,
    const int* __restrict__ slots,
    v4f*       __restrict__ out4)
{
    const int base = blockIdx.x * CHUNK + threadIdx.x;

    #pragma unroll 1
    for (int k = 0; k < CHUNK / 256; k += MLP) {
        int  ii[MLP];
        v4f  vv[MLP];
        int  pp[MLP];
        int  nn[MLP];

        // Issue all yb loads back-to-back (8 KB in flight per wave).
        #pragma unroll
        for (int j = 0; j < MLP; ++j) {
            ii[j] = base + (k + j) * 256;
            vv[j] = __builtin_nontemporal_load(yb4 + ii[j]);
        }
        // Issue all (L2-hot) count loads.
        #pragma unroll
        for (int j = 0; j < MLP; ++j) {
            pp[j] = pos_of(ii[j]);
            nn[j] = cnt[pp[j]];
        }
        // Gather-add matching x blocks.
        #pragma unroll
        for (int j = 0; j < MLP; ++j) {
            int nm = nn[j];
            if (nm) {
                if (nm > MAXDUP) nm = MAXDUP;
                const int bx = xbase_of(ii[j]);
                const int* __restrict__ sl = slots + pp[j] * MAXDUP;
                for (int m = 0; m < nm; ++m) vv[j] += x4[sl[m] * 4096 + bx];
            }
        }
        // Stream out.
        #pragma unroll
        for (int j = 0; j < MLP; ++j)
            __builtin_nontemporal_store(vv[j], out4 + ii[j]);
    }
}

extern "C" void kernel_launch(void* const* d_in, const int* in_sizes, int n_in,
                              void* d_out, int out_size, void* d_ws, size_t ws_size,
                              hipStream_t stream) {
    const float* x   = (const float*)d_in[0];
    const float* yb  = (const float*)d_in[1];
    const int*   idx = (const int*)d_in[2];
    float*       out = (float*)d_out;

    const int N = in_sizes[2] / 3;   // 4096

    int* cnt   = (int*)d_ws;
    int* slots = cnt + NPOS;

    zero_counts<<<(NPOS + 255) / 256, 256, 0, stream>>>(cnt);
    build_lists<<<(N + 255) / 256, 256, 0, stream>>>(idx, cnt, slots, N);
    sort_lists<<<(NPOS + 255) / 256, 256, 0, stream>>>(cnt, slots);

    scatter_main<<<WGS, 256, 0, stream>>>(
        (const v4f*)x, (const v4f*)yb, cnt, slots, (v4f*)out);
}

// Round 6
// 255.752 us; speedup vs baseline: 1.2077x; 1.2077x over previous
//
#include <hip/hip_runtime.h>

// Problem:
//   x:       (N=4096, C=64, 16, 16) f32
//   y_base:  (B=8, C=64, H=512, W=512) f32
//   indices: (N,3) int32 [b, r, c]; block origin (r*16, c*16); st==bs==16, off==0
//   out = y_base; out[b, :, r*16+i, c*16+j] += x[n, :, i, j]  (dups accumulate,
//   in index order n ascending -> we keep ids sorted ascending = bit-exact)
//
// Inverted-list + output-linear streaming. This round: one-load int4
// descriptor per position + branch-free speculative first x-load; MLP=4.

#define NPOS   8192
#define MAXDUP 8
#define OUT4   33554432            // 8*64*512*512 / 4
#define WGS    4096
#define CHUNK  (OUT4 / WGS)        // 8192 float4 per WG (128 KB)
#define MLP    4

typedef float v4f __attribute__((ext_vector_type(4)));

__global__ void zero_counts(int* __restrict__ cnt) {
    int i = blockIdx.x * 256 + threadIdx.x;
    if (i < NPOS) cnt[i] = 0;
}

__global__ void build_lists(const int* __restrict__ idx, int* __restrict__ cnt,
                            int* __restrict__ slots, int N) {
    int n = blockIdx.x * 256 + threadIdx.x;
    if (n >= N) return;
    const int b = idx[3 * n], r = idx[3 * n + 1], c = idx[3 * n + 2];
    const int pos = b * 1024 + r * 32 + c;
    const int s = atomicAdd(&cnt[pos], 1);
    if (s < MAXDUP) slots[pos * MAXDUP + s] = n;
}

// Sort each list ascending (== np.add.at order -> bit-exact), then pack a
// 16B descriptor: ids, -1 padding; d.x = -2 means ">4 matches, use slots".
__global__ void sort_pack(int* __restrict__ cnt, int* __restrict__ slots,
                          int4* __restrict__ desc) {
    int p = blockIdx.x * 256 + threadIdx.x;
    if (p >= NPOS) return;
    int nm = cnt[p]; if (nm > MAXDUP) nm = MAXDUP;
    int* s = slots + p * MAXDUP;
    for (int i = 1; i < nm; ++i) {
        const int key = s[i];
        int j = i - 1;
        while (j >= 0 && s[j] > key) { s[j + 1] = s[j]; --j; }
        s[j + 1] = key;
    }
    int4 d = make_int4(-1, -1, -1, -1);
    if (nm > 4) {
        d.x = -2;
    } else {
        if (nm > 0) d.x = s[0];
        if (nm > 1) d.y = s[1];
        if (nm > 2) d.z = s[2];
        if (nm > 3) d.w = s[3];
    }
    desc[p] = d;
}

__device__ __forceinline__ int pos_of(int i) {
    // i (float4 idx) bits: [b:3][c:6][h:9][w4:7]
    return (i >> 22) * 1024 + ((i >> 11) & 31) * 32 + ((i >> 2) & 31);
}
__device__ __forceinline__ int xbase_of(int i) {
    // float4 offset inside an x block: c*64 + (h&15)*4 + (w4&3)
    return ((i >> 16) & 63) * 64 + ((i >> 7) & 15) * 4 + (i & 3);
}

__global__ __launch_bounds__(256) void scatter_main(
    const v4f*  __restrict__ x4,
    const v4f*  __restrict__ yb4,
    const int*  __restrict__ cnt,
    const int*  __restrict__ slots,
    const int4* __restrict__ desc,
    v4f*        __restrict__ out4)
{
    const int base = blockIdx.x * CHUNK + threadIdx.x;

    #pragma unroll 1
    for (int k = 0; k < CHUNK / 256; k += MLP) {
        int  ii[MLP], pp[MLP], bx[MLP];
        v4f  vv[MLP], xv[MLP];
        int4 dd[MLP];

        // 4 yb streaming loads in flight
        #pragma unroll
        for (int j = 0; j < MLP; ++j) {
            ii[j] = base + (k + j) * 256;
            vv[j] = __builtin_nontemporal_load(yb4 + ii[j]);
        }
        // 4 descriptor loads (L2-hot, single hop)
        #pragma unroll
        for (int j = 0; j < MLP; ++j) {
            pp[j] = pos_of(ii[j]);
            bx[j] = xbase_of(ii[j]);
            dd[j] = desc[pp[j]];
        }
        // speculative first x-load for all j (branch-free issue)
        #pragma unroll
        for (int j = 0; j < MLP; ++j) {
            const int id = dd[j].x < 0 ? 0 : dd[j].x;
            xv[j] = x4[id * 4096 + bx[j]];
        }
        // accumulate (ids ascending == reference order)
        #pragma unroll
        for (int j = 0; j < MLP; ++j) {
            if (dd[j].x >= 0) vv[j] += xv[j];
            if (dd[j].x == -2) {
                int nm = cnt[pp[j]]; if (nm > MAXDUP) nm = MAXDUP;
                const int* __restrict__ sl = slots + pp[j] * MAXDUP;
                for (int m = 0; m < nm; ++m) vv[j] += x4[sl[m] * 4096 + bx[j]];
            } else if (dd[j].y >= 0) {
                vv[j] += x4[dd[j].y * 4096 + bx[j]];
                if (dd[j].z >= 0) {
                    vv[j] += x4[dd[j].z * 4096 + bx[j]];
                    if (dd[j].w >= 0) vv[j] += x4[dd[j].w * 4096 + bx[j]];
                }
            }
        }
        #pragma unroll
        for (int j = 0; j < MLP; ++j)
            __builtin_nontemporal_store(vv[j], out4 + ii[j]);
    }
}

extern "C" void kernel_launch(void* const* d_in, const int* in_sizes, int n_in,
                              void* d_out, int out_size, void* d_ws, size_t ws_size,
                              hipStream_t stream) {
    const float* x   = (const float*)d_in[0];
    const float* yb  = (const float*)d_in[1];
    const int*   idx = (const int*)d_in[2];
    float*       out = (float*)d_out;

    const int N = in_sizes[2] / 3;   // 4096

    // ws layout (416 KB total): cnt[8192] | slots[8192*8] | desc int4[8192]
    int*  cnt   = (int*)d_ws;
    int*  slots = cnt + NPOS;
    int4* desc  = (int4*)(slots + NPOS * MAXDUP);

    zero_counts<<<(NPOS + 255) / 256, 256, 0, stream>>>(cnt);
    build_lists<<<(N + 255) / 256, 256, 0, stream>>>(idx, cnt, slots, N);
    sort_pack<<<(NPOS + 255) / 256, 256, 0, stream>>>(cnt, slots, desc);

    scatter_main<<<WGS, 256, 0, stream>>>(
        (const v4f*)x, (const v4f*)yb, cnt, slots, desc, (v4f*)out);
}

// Round 7
// 232.250 us; speedup vs baseline: 1.3299x; 1.1012x over previous
//
#include <hip/hip_runtime.h>

// Problem:
//   x:       (N=4096, C=64, 16, 16) f32
//   y_base:  (B=8, C=64, H=512, W=512) f32
//   indices: (N,3) int32 [b, r, c]; origin (r*16, c*16); st==bs==16, off==0
//   out = y_base; out[b, :, r*16+i, c*16+j] += x[n, :, i, j]  (dups accumulate
//   in ascending n order -> ids kept sorted ascending = bit-exact)
//
// Inverted-list + output-linear streaming. This round: tile position is
// constant for 8 consecutive k-steps per thread -> hoist desc to once per
// group and prefetch next group's desc; inner loop is pure streaming with
// known x addresses (no metadata wait on the critical path).

#define NPOS   8192
#define MAXDUP 8
#define OUT4   33554432            // 8*64*512*512 / 4
#define WGS    4096
#define CHUNK  (OUT4 / WGS)        // 8192 float4 per WG (128 KB)
#define NG     4                   // pos-groups per thread: CHUNK/256/8

typedef float v4f __attribute__((ext_vector_type(4)));

__global__ void build_lists(const int* __restrict__ idx, int* __restrict__ cnt,
                            int* __restrict__ slots, int N) {
    int n = blockIdx.x * 256 + threadIdx.x;
    if (n >= N) return;
    const int b = idx[3 * n], r = idx[3 * n + 1], c = idx[3 * n + 2];
    const int pos = b * 1024 + r * 32 + c;
    const int s = atomicAdd(&cnt[pos], 1);
    if (s < MAXDUP) slots[pos * MAXDUP + s] = n;
}

// Sort each list ascending, pack 16B descriptor: ids, -1 pad; -2 = overflow.
__global__ void sort_pack(int* __restrict__ cnt, int* __restrict__ slots,
                          int4* __restrict__ desc) {
    int p = blockIdx.x * 256 + threadIdx.x;
    if (p >= NPOS) return;
    int nm = cnt[p]; if (nm > MAXDUP) nm = MAXDUP;
    int* s = slots + p * MAXDUP;
    for (int i = 1; i < nm; ++i) {
        const int key = s[i];
        int j = i - 1;
        while (j >= 0 && s[j] > key) { s[j + 1] = s[j]; --j; }
        s[j + 1] = key;
    }
    int4 d = make_int4(-1, -1, -1, -1);
    if (nm > 4) {
        d.x = -2;
    } else {
        if (nm > 0) d.x = s[0];
        if (nm > 1) d.y = s[1];
        if (nm > 2) d.z = s[2];
        if (nm > 3) d.w = s[3];
    }
    desc[p] = d;
}

__device__ __forceinline__ int pos_of(int i) {
    // i (float4 idx) bits: [b:3][c:6][h:9][w4:7]
    return (i >> 22) * 1024 + ((i >> 11) & 31) * 32 + ((i >> 2) & 31);
}
__device__ __forceinline__ int xbase_of(int i) {
    // float4 offset inside an x block: c*64 + (h&15)*4 + (w4&3)
    return ((i >> 16) & 63) * 64 + ((i >> 7) & 15) * 4 + (i & 3);
}

__global__ __launch_bounds__(256) void scatter_main(
    const v4f*  __restrict__ x4,
    const v4f*  __restrict__ yb4,
    const int*  __restrict__ cnt,
    const int*  __restrict__ slots,
    const int4* __restrict__ desc,
    v4f*        __restrict__ out4)
{
    const int base = blockIdx.x * CHUNK + threadIdx.x;

    // First group's descriptor (pos is constant across each 8-k group:
    // h advances by 2 per k, h>>4 flips every 8 k's; b,c,w4 fixed per thread).
    int4 d = desc[pos_of(base)];

    #pragma unroll 1
    for (int g = 0; g < NG; ++g) {
        const int i0  = base + g * 2048;      // 8 * 256
        const int bxb = xbase_of(i0);

        // Prefetch next group's descriptor (ready by the time we need it).
        int4 dn = d;
        if (g + 1 < NG) dn = desc[pos_of(i0 + 2048)];

        const int id0 = d.x < 0 ? 0 : d.x;    // speculative (block 0 is L2-hot)

        #pragma unroll
        for (int half = 0; half < 2; ++half) {
            int ii[4];
            v4f v[4], xv[4];

            #pragma unroll
            for (int j = 0; j < 4; ++j) {
                ii[j] = i0 + (half * 4 + j) * 256;
                v[j]  = __builtin_nontemporal_load(yb4 + ii[j]);
            }
            #pragma unroll
            for (int j = 0; j < 4; ++j)
                xv[j] = x4[id0 * 4096 + bxb + (half * 4 + j) * 8];

            if (d.x == -2) {
                // rare overflow (>4 dups): full sorted list
                const int p = pos_of(i0);
                int nm = cnt[p]; if (nm > MAXDUP) nm = MAXDUP;
                const int* __restrict__ sl = slots + p * MAXDUP;
                for (int m = 0; m < nm; ++m) {
                    #pragma unroll
                    for (int j = 0; j < 4; ++j)
                        v[j] += x4[sl[m] * 4096 + bxb + (half * 4 + j) * 8];
                }
            } else {
                if (d.x >= 0) {
                    #pragma unroll
                    for (int j = 0; j < 4; ++j) v[j] += xv[j];
                }
                if (d.y >= 0) {
                    #pragma unroll
                    for (int j = 0; j < 4; ++j)
                        v[j] += x4[d.y * 4096 + bxb + (half * 4 + j) * 8];
                    if (d.z >= 0) {
                        #pragma unroll
                        for (int j = 0; j < 4; ++j)
                            v[j] += x4[d.z * 4096 + bxb + (half * 4 + j) * 8];
                        if (d.w >= 0) {
                            #pragma unroll
                            for (int j = 0; j < 4; ++j)
                                v[j] += x4[d.w * 4096 + bxb + (half * 4 + j) * 8];
                        }
                    }
                }
            }

            #pragma unroll
            for (int j = 0; j < 4; ++j)
                __builtin_nontemporal_store(v[j], out4 + ii[j]);
        }

        d = dn;
    }
}

extern "C" void kernel_launch(void* const* d_in, const int* in_sizes, int n_in,
                              void* d_out, int out_size, void* d_ws, size_t ws_size,
                              hipStream_t stream) {
    const float* x   = (const float*)d_in[0];
    const float* yb  = (const float*)d_in[1];
    const int*   idx = (const int*)d_in[2];
    float*       out = (float*)d_out;

    const int N = in_sizes[2] / 3;   // 4096

    // ws layout: cnt[8192] | slots[8192*8] | desc int4[8192]  (416 KB)
    int*  cnt   = (int*)d_ws;
    int*  slots = cnt + NPOS;
    int4* desc  = (int4*)(slots + NPOS * MAXDUP);

    hipMemsetAsync(cnt, 0, NPOS * sizeof(int), stream);
    build_lists<<<(N + 255) / 256, 256, 0, stream>>>(idx, cnt, slots, N);
    sort_pack<<<(NPOS + 255) / 256, 256, 0, stream>>>(cnt, slots, desc);

    scatter_main<<<WGS, 256, 0, stream>>>(
        (const v4f*)x, (const v4f*)yb, cnt, slots, desc, (v4f*)out);
}

// Round 8
// 229.970 us; speedup vs baseline: 1.3431x; 1.0099x over previous
//
#include <hip/hip_runtime.h>

// Problem:
//   x:       (N=4096, C=64, 16, 16) f32
//   y_base:  (B=8, C=64, H=512, W=512) f32
//   indices: (N,3) int32 [b, r, c]; origin (r*16, c*16); st==bs==16, off==0
//   out = y_base; out[b, :, r*16+i, c*16+j] += x[n, :, i, j]  (dups accumulate
//   in ascending n order -> ids kept sorted ascending = bit-exact)
//
// Inverted-list + output-linear streaming, desc hoisted per 8-k group.
// This round: software-pipeline yb NT loads one step ahead so the
// per-step wait covers only the (L3/L2-hot) x gather, not HBM latency.

#define NPOS   8192
#define MAXDUP 8
#define OUT4   33554432            // 8*64*512*512 / 4
#define WGS    4096
#define CHUNK  (OUT4 / WGS)        // 8192 float4 per WG (128 KB)
#define NG     4                   // pos-groups per thread (8 k-steps each)
#define STEPS  (NG * 2)            // one step = 4 float4 per thread

typedef float v4f __attribute__((ext_vector_type(4)));

__global__ void build_lists(const int* __restrict__ idx, int* __restrict__ cnt,
                            int* __restrict__ slots, int N) {
    int n = blockIdx.x * 256 + threadIdx.x;
    if (n >= N) return;
    const int b = idx[3 * n], r = idx[3 * n + 1], c = idx[3 * n + 2];
    const int pos = b * 1024 + r * 32 + c;
    const int s = atomicAdd(&cnt[pos], 1);
    if (s < MAXDUP) slots[pos * MAXDUP + s] = n;
}

// Sort each list ascending, pack 16B descriptor: ids, -1 pad; -2 = overflow.
__global__ void sort_pack(int* __restrict__ cnt, int* __restrict__ slots,
                          int4* __restrict__ desc) {
    int p = blockIdx.x * 256 + threadIdx.x;
    if (p >= NPOS) return;
    int nm = cnt[p]; if (nm > MAXDUP) nm = MAXDUP;
    int* s = slots + p * MAXDUP;
    for (int i = 1; i < nm; ++i) {
        const int key = s[i];
        int j = i - 1;
        while (j >= 0 && s[j] > key) { s[j + 1] = s[j]; --j; }
        s[j + 1] = key;
    }
    int4 d = make_int4(-1, -1, -1, -1);
    if (nm > 4) {
        d.x = -2;
    } else {
        if (nm > 0) d.x = s[0];
        if (nm > 1) d.y = s[1];
        if (nm > 2) d.z = s[2];
        if (nm > 3) d.w = s[3];
    }
    desc[p] = d;
}

__device__ __forceinline__ int pos_of(int i) {
    // i (float4 idx) bits: [b:3][c:6][h:9][w4:7]
    return (i >> 22) * 1024 + ((i >> 11) & 31) * 32 + ((i >> 2) & 31);
}
__device__ __forceinline__ int xbase_of(int i) {
    // float4 offset inside an x block: c*64 + (h&15)*4 + (w4&3)
    return ((i >> 16) & 63) * 64 + ((i >> 7) & 15) * 4 + (i & 3);
}

__global__ __launch_bounds__(256) void scatter_main(
    const v4f*  __restrict__ x4,
    const v4f*  __restrict__ yb4,
    const int*  __restrict__ cnt,
    const int*  __restrict__ slots,
    const int4* __restrict__ desc,
    v4f*        __restrict__ out4)
{
    const int base = blockIdx.x * CHUNK + threadIdx.x;

    // Descriptor for group 0 (pos constant across each 8-k group).
    int4 d  = desc[pos_of(base)];
    int4 dn = d;

    // Prologue: yb loads for step 0.
    v4f vA[4];
    #pragma unroll
    for (int j = 0; j < 4; ++j)
        vA[j] = __builtin_nontemporal_load(yb4 + base + j * 256);

    #pragma unroll 1
    for (int s = 0; s < STEPS; ++s) {
        const int g    = s >> 1;
        const int half = s & 1;
        const int i0   = base + g * 2048;
        const int bxb  = xbase_of(i0) + half * 32;
        const int id0  = d.x < 0 ? 0 : d.x;   // speculative (L2-hot block 0)

        // x gather for current step (d known a group ahead).
        v4f xv[4];
        #pragma unroll
        for (int j = 0; j < 4; ++j)
            xv[j] = x4[id0 * 4096 + bxb + j * 8];

        // Prefetch next group's descriptor early in the group.
        if (half == 0 && g + 1 < NG) dn = desc[pos_of(i0 + 2048)];

        // Issue NEXT step's yb loads before consuming this step's data:
        // the consume-wait then leaves these (and nothing we need now)
        // in flight -> yb HBM latency off the critical path.
        v4f vB[4];
        if (s + 1 < STEPS) {
            const int nb = base + (s + 1) * 1024;
            #pragma unroll
            for (int j = 0; j < 4; ++j)
                vB[j] = __builtin_nontemporal_load(yb4 + nb + j * 256);
        }

        // Accumulate (ids ascending == reference np.add.at order).
        if (d.x == -2) {
            // rare overflow (>4 dups): full sorted list
            const int p = pos_of(i0);
            int nm = cnt[p]; if (nm > MAXDUP) nm = MAXDUP;
            const int* __restrict__ sl = slots + p * MAXDUP;
            for (int m = 0; m < nm; ++m) {
                #pragma unroll
                for (int j = 0; j < 4; ++j)
                    vA[j] += x4[sl[m] * 4096 + bxb + j * 8];
            }
        } else {
            if (d.x >= 0) {
                #pragma unroll
                for (int j = 0; j < 4; ++j) vA[j] += xv[j];
            }
            if (d.y >= 0) {
                #pragma unroll
                for (int j = 0; j < 4; ++j)
                    vA[j] += x4[d.y * 4096 + bxb + j * 8];
                if (d.z >= 0) {
                    #pragma unroll
                    for (int j = 0; j < 4; ++j)
                        vA[j] += x4[d.z * 4096 + bxb + j * 8];
                    if (d.w >= 0) {
                        #pragma unroll
                        for (int j = 0; j < 4; ++j)
                            vA[j] += x4[d.w * 4096 + bxb + j * 8];
                    }
                }
            }
        }

        // Store current step.
        {
            const int sb = base + s * 1024;
            #pragma unroll
            for (int j = 0; j < 4; ++j)
                __builtin_nontemporal_store(vA[j], out4 + sb + j * 256);
        }

        // Rotate pipeline registers.
        if (s + 1 < STEPS) {
            #pragma unroll
            for (int j = 0; j < 4; ++j) vA[j] = vB[j];
        }
        if (half == 1) d = dn;
    }
}

extern "C" void kernel_launch(void* const* d_in, const int* in_sizes, int n_in,
                              void* d_out, int out_size, void* d_ws, size_t ws_size,
                              hipStream_t stream) {
    const float* x   = (const float*)d_in[0];
    const float* yb  = (const float*)d_in[1];
    const int*   idx = (const int*)d_in[2];
    float*       out = (float*)d_out;

    const int N = in_sizes[2] / 3;   // 4096

    // ws layout: cnt[8192] | slots[8192*8] | desc int4[8192]  (416 KB)
    int*  cnt   = (int*)d_ws;
    int*  slots = cnt + NPOS;
    int4* desc  = (int4*)(slots + NPOS * MAXDUP);

    hipMemsetAsync(cnt, 0, NPOS * sizeof(int), stream);
    build_lists<<<(N + 255) / 256, 256, 0, stream>>>(idx, cnt, slots, N);
    sort_pack<<<(NPOS + 255) / 256, 256, 0, stream>>>(cnt, slots, desc);

    scatter_main<<<WGS, 256, 0, stream>>>(
        (const v4f*)x, (const v4f*)yb, cnt, slots, desc, (v4f*)out);
}